// Round 8
// baseline (3011.145 us; speedup 1.0000x reference)
//
#include <hip/hip_runtime.h>
#include <stdint.h>

typedef unsigned int u32;
typedef unsigned long long u64;
typedef unsigned short u16;
typedef __attribute__((ext_vector_type(8))) short bf16x8;
typedef __attribute__((ext_vector_type(4))) float f32x4;
typedef __attribute__((ext_vector_type(2))) float f32x2;
typedef __attribute__((ext_vector_type(4))) u16 u16x4;

// Problem constants
#define T_STEPS 512
#define BATCH   64
#define IDIM    512
#define HDIM    1024
#define GDIM    4096   // 4*H
#define KDIM    1536   // I+H
#define NWG     256    // 8 batch-groups x 32 h-shards, 1 WG/CU (proven chassis)

// ws layout (bytes)
#define GB_OFF  0u                    // Gx bf16 [32768][4096]  = 268435456
#define XB_OFF  268435456u            // X bf16  [32768][512]   = 33554432
#define WX_OFF  301989888u            // Wx bf16 [4096][512]    = 4194304 (dead after gemm)
// tagged h exchange overlays the dead Wx region after k_gemm_gx:
// u32 [2][8 groups][8 rows][1024 cols] = 524288 bytes
#define HSEQ_OFF WX_OFF

__device__ __forceinline__ u16 f2bf(float f) {
  union { float f; u32 u; } v; v.f = f;
  return (u16)((v.u + 0x7fffu + ((v.u >> 16) & 1u)) >> 16);   // RNE
}
__device__ __forceinline__ float bf2f(u16 h) {
  union { u32 u; float f; } v; v.u = ((u32)h) << 16; return v.f;
}
__device__ __forceinline__ u32 FU(float f) {
  union { float f; u32 u; } v; v.f = f; return v.u;
}
__device__ __forceinline__ float UF(u32 u) {
  union { u32 u; float f; } v; v.u = u; return v.f;
}

#define GLDS(g, l) __builtin_amdgcn_global_load_lds( \
    (const __attribute__((address_space(1))) u32*)(g), \
    (__attribute__((address_space(3))) u32*)(l), 16, 0, 0)

// ---------------- Phase A: conversions / init ----------------
__global__ void k_cvt4(const float* __restrict__ src, u16* __restrict__ dst, int n4) {
  int i = blockIdx.x * blockDim.x + threadIdx.x;
  int stride = gridDim.x * blockDim.x;
  for (; i < n4; i += stride) {
    float4 v = reinterpret_cast<const float4*>(src)[i];
    u16x4 o; o.x = f2bf(v.x); o.y = f2bf(v.y); o.z = f2bf(v.z); o.w = f2bf(v.w);
    reinterpret_cast<u16x4*>(dst)[i] = o;
  }
}

__global__ void k_cvt_wx(const float* __restrict__ W, u16* __restrict__ wxb) {
  int i = blockIdx.x * blockDim.x + threadIdx.x;   // over 4096*128 float4 groups
  if (i >= GDIM * (IDIM / 4)) return;
  int row = i >> 7, cg = i & 127;
  float4 v = *reinterpret_cast<const float4*>(W + (size_t)row * KDIM + cg * 4);
  u16x4 o; o.x = f2bf(v.x); o.y = f2bf(v.y); o.z = f2bf(v.z); o.w = f2bf(v.w);
  *reinterpret_cast<u16x4*>(wxb + (size_t)row * IDIM + cg * 4) = o;
}

__global__ void k_zero(u32* __restrict__ p, int n) {
  int i = blockIdx.x * blockDim.x + threadIdx.x;
  int stride = gridDim.x * blockDim.x;
  for (; i < n; i += stride) p[i] = 0u;
}

// ---------------- Phase B: Gx = Xbf16 @ Wx^T + b (bf16 out) ----------------
// M=32768, N=4096, K=512. 128x128 tile, BK=64, 4 waves each 64x64.
__global__ void k_gemm_gx(const u16* __restrict__ Xb, const u16* __restrict__ Wxb,
                          const float* __restrict__ bias, u16* __restrict__ Gb) {
  __shared__ u16 lA[128 * 64];
  __shared__ u16 lB[128 * 64];
  const int tid = threadIdx.x;
  const int wv = tid >> 6, l = tid & 63;
  const int ln = l & 15, lg = l >> 4;
  const int m0 = blockIdx.x * 128, n0 = blockIdx.y * 128;
  const int wr = wv >> 1, wc = wv & 1;

  f32x4 acc[4][4];
  #pragma unroll
  for (int mi = 0; mi < 4; ++mi)
    #pragma unroll
    for (int nj = 0; nj < 4; ++nj) acc[mi][nj] = (f32x4){0.f, 0.f, 0.f, 0.f};

  for (int kt = 0; kt < 8; ++kt) {
    #pragma unroll
    for (int it = 0; it < 4; ++it) {
      int off = it * 4096 + tid * 16;      // byte offset in 16KB tile
      int row = off >> 7;                  // 128 B per row (64 bf16)
      int col = (off & 127) >> 1;          // bf16 col
      GLDS(Xb  + (size_t)(m0 + row) * IDIM + kt * 64 + col, (char*)lA + off);
      GLDS(Wxb + (size_t)(n0 + row) * IDIM + kt * 64 + col, (char*)lB + off);
    }
    asm volatile("s_waitcnt vmcnt(0)" ::: "memory");
    __syncthreads();
    #pragma unroll
    for (int ks = 0; ks < 2; ++ks) {
      bf16x8 af[4], bfr[4];
      #pragma unroll
      for (int mi = 0; mi < 4; ++mi)
        af[mi] = *reinterpret_cast<const bf16x8*>(&lA[(wr * 64 + mi * 16 + ln) * 64 + ks * 32 + lg * 8]);
      #pragma unroll
      for (int nj = 0; nj < 4; ++nj)
        bfr[nj] = *reinterpret_cast<const bf16x8*>(&lB[(wc * 64 + nj * 16 + ln) * 64 + ks * 32 + lg * 8]);
      #pragma unroll
      for (int mi = 0; mi < 4; ++mi)
        #pragma unroll
        for (int nj = 0; nj < 4; ++nj)
          acc[mi][nj] = __builtin_amdgcn_mfma_f32_16x16x32_bf16(af[mi], bfr[nj], acc[mi][nj], 0, 0, 0);
    }
    __syncthreads();
  }
  float bv[4];
  #pragma unroll
  for (int nj = 0; nj < 4; ++nj) bv[nj] = bias[n0 + wc * 64 + nj * 16 + ln];
  #pragma unroll
  for (int mi = 0; mi < 4; ++mi)
    #pragma unroll
    for (int r = 0; r < 4; ++r) {
      int m = m0 + wr * 64 + mi * 16 + lg * 4 + r;
      #pragma unroll
      for (int nj = 0; nj < 4; ++nj)
        Gb[(size_t)m * GDIM + n0 + wc * 64 + nj * 16 + ln] = f2bf(acc[mi][nj][r] + bv[nj]);
    }
}

// ---------------- Phase C: persistent recurrent kernel ----------------
// 256 WGs = 8 batch-groups(g = w&7: 8 rows) x 32 h-shards(j = w>>3: 32 h).
// DATA IS THE FLAG, writes execute AT the IC (tagged u32, atomic swap,
// ack==visible — proven R6/R7). This round:
//  - Gx(t+1) loads issued right after acc-init (consume point), so their HBM
//    latency hides under MFMA+EW instead of inflating the first poll quantum.
//  - Per-lane 4B atomic swaps (lane n<8 owns col h0w+n): deletes the col-pair
//    pack shuffles from the EW dependent chain; consumer format unchanged.
__launch_bounds__(256, 1)
__global__ void k_lstm(const u16* __restrict__ Gb,    // [32768][4096] bf16
                       const float* __restrict__ W,   // [4096][1536] fp32
                       u32* __restrict__ hseq,        // [2][8][8][1024] tagged u32
                       float* __restrict__ out) {
  __shared__ f32x4 As[2][2048];   // 2 x 32 KB; slot byte = ((c8*16+row)<<4) ^ ((c8&7)<<4)
  const int tid = threadIdx.x;
  const int w = blockIdx.x;
  const int g = w & 7;                           // batch group: rows [8g, 8g+8)
  const int j = w >> 3;                          // h-shard: h [32j, 32j+32)
  const int wv = tid >> 6, l = tid & 63;
  const int n = l & 15, lg = l >> 4;
  const int h0w = j * 32 + wv * 8;               // this wave's 8 h-cols
  const int jcol0 = (n >> 3) * HDIM + h0w + (n & 7);        // f / i gate rows
  const int jcol1 = (2 + (n >> 3)) * HDIM + h0w + (n & 7);  // g / o gate rows

  // --- preload W_h fragments into registers (once): 2 x 32 x bf16x8 ---
  bf16x8 w0[32], w1[32];
  #pragma unroll
  for (int ks = 0; ks < 32; ++ks) {
    const float* wp = W + (size_t)jcol0 * KDIM + IDIM + ks * 32 + lg * 8;
    float4 v0 = *reinterpret_cast<const float4*>(wp);
    float4 v1 = *reinterpret_cast<const float4*>(wp + 4);
    bf16x8 fr;
    fr[0] = (short)f2bf(v0.x); fr[1] = (short)f2bf(v0.y);
    fr[2] = (short)f2bf(v0.z); fr[3] = (short)f2bf(v0.w);
    fr[4] = (short)f2bf(v1.x); fr[5] = (short)f2bf(v1.y);
    fr[6] = (short)f2bf(v1.z); fr[7] = (short)f2bf(v1.w);
    w0[ks] = fr;
  }
  #pragma unroll
  for (int ks = 0; ks < 32; ++ks) {
    const float* wp = W + (size_t)jcol1 * KDIM + IDIM + ks * 32 + lg * 8;
    float4 v0 = *reinterpret_cast<const float4*>(wp);
    float4 v1 = *reinterpret_cast<const float4*>(wp + 4);
    bf16x8 fr;
    fr[0] = (short)f2bf(v0.x); fr[1] = (short)f2bf(v0.y);
    fr[2] = (short)f2bf(v0.z); fr[3] = (short)f2bf(v0.w);
    fr[4] = (short)f2bf(v1.x); fr[5] = (short)f2bf(v1.y);
    fr[6] = (short)f2bf(v1.z); fr[7] = (short)f2bf(v1.w);
    w1[ks] = fr;
  }

  // zero BOTH As buffers once: pad rows (slot row>=8) must read as 0 forever;
  // staged writes (row<8) only touch row<8 slots (swizzle keeps q^(c8&7)<8)
  {
    f32x4* ap = &As[0][0];
    #pragma unroll
    for (int i = 0; i < 16; ++i)
      ap[i * 256 + tid] = (f32x4){0.f, 0.f, 0.f, 0.f};
  }
  __syncthreads();

  float cx[4] = {0.f, 0.f, 0.f, 0.f};

  // Gx(0) prefetch into registers (plain cached loads)
  u16 ga[4] = {0, 0, 0, 0}, gb_[4] = {0, 0, 0, 0};
  if (lg < 2) {
    #pragma unroll
    for (int r = 0; r < 4; ++r) {
      int ba = g * 8 + lg * 4 + r;
      ga[r]  = Gb[(size_t)ba * GDIM + jcol0];
      gb_[r] = Gb[(size_t)ba * GDIM + jcol1];
    }
  }

  #pragma unroll 1
  for (int t = 0; t < T_STEPS; ++t) {
    // ---- tagged-data poll: coalesced read of the 32KB group slice ----
    // thread tid owns chunk (row q, cols 4*tid..4*tid+4) for q = 0..7.
    // Gx loads were issued an iteration ago (post acc-init) and have already
    // completed under MFMA+EW, so vmcnt(0) here is a pure IC-read wait.
    const char* bbase = (const char*)(hseq + (size_t)(t & 1) * 65536
                                      + (size_t)g * 8192);
    const u32 tt = (u32)t << 16;
    f32x4 ld[8];
    u32 need = 0xffu, spin = 0;
    while (true) {
      #pragma unroll
      for (int q = 0; q < 8; ++q)
        if (need & (1u << q))
          asm volatile("global_load_dwordx4 %0, %1, off sc0 sc1"
                       : "=&v"(ld[q]) : "v"(bbase + q * 4096 + tid * 16) : "memory");
      asm volatile("s_waitcnt vmcnt(0)" ::: "memory");
      __builtin_amdgcn_sched_barrier(0);
      u32 bad = 0;
      #pragma unroll
      for (int q = 0; q < 8; ++q)
        if (need & (1u << q)) {
          u32 m = ((FU(ld[q].x) ^ tt) | (FU(ld[q].y) ^ tt)
                 | (FU(ld[q].z) ^ tt) | (FU(ld[q].w) ^ tt)) & 0xffff0000u;
          if (m) bad |= (1u << q);
        }
      need = bad;
      if (__all((int)(need == 0u))) break;   // wave-uniform exit
      if (++spin > (1u << 17)) break;        // bounded: fail visibly, never hang
    }

    // ---- stage payload (low16) into swizzled LDS fragment slots ----
    char* lbase = (char*)&As[t & 1][0];
    const int col8 = tid >> 1, half = tid & 1;
    const u32 sbase = (u32)(col8 * 256 + half * 8);
    #pragma unroll
    for (int q = 0; q < 8; ++q) {
      u32 a = FU(ld[q].x), b = FU(ld[q].y), c = FU(ld[q].z), d = FU(ld[q].w);
      f32x2 pk2 = { UF((a & 0xffffu) | (b << 16)), UF((c & 0xffffu) | (d << 16)) };
      u32 off = sbase + (u32)((q ^ (col8 & 7)) * 16);
      *reinterpret_cast<f32x2*>(lbase + off) = pk2;
    }
    __syncthreads();   // the ONLY barrier per step (As is double-buffered)

    // gates = Gx + hx @ Wh^T : 2 N-tiles x 32 ks, 4 independent MFMA chains
    f32x4 c00 = {bf2f(ga[0]),  bf2f(ga[1]),  bf2f(ga[2]),  bf2f(ga[3])};
    f32x4 c10 = {bf2f(gb_[0]), bf2f(gb_[1]), bf2f(gb_[2]), bf2f(gb_[3])};
    f32x4 c01 = {0.f, 0.f, 0.f, 0.f}, c11 = c01;

    // Gx(t+1): issue NOW (ga/gb_ just consumed) so HBM latency hides under
    // the MFMA + EW phase instead of the next poll's vmcnt(0).
    {
      int tn = (t < T_STEPS - 1) ? t + 1 : t;
      if (lg < 2) {
        #pragma unroll
        for (int r = 0; r < 4; ++r) {
          int ba = g * 8 + lg * 4 + r;
          const u16* gp = Gb + ((size_t)tn * BATCH + ba) * GDIM;
          ga[r]  = gp[jcol0];
          gb_[r] = gp[jcol1];
        }
      }
    }

    #pragma unroll
    for (int ks = 0; ks < 32; ks += 2) {
      int c8a = 4 * (ks + 0) + lg;
      int c8b = 4 * (ks + 1) + lg;
      u32 ba_ = (u32)(((c8a * 16 + n) << 4) ^ ((c8a & 7) << 4));
      u32 bb_ = (u32)(((c8b * 16 + n) << 4) ^ ((c8b & 7) << 4));
      bf16x8 f0 = *reinterpret_cast<const bf16x8*>(lbase + ba_);
      bf16x8 f1 = *reinterpret_cast<const bf16x8*>(lbase + bb_);
      c00 = __builtin_amdgcn_mfma_f32_16x16x32_bf16(f0, w0[ks + 0], c00, 0, 0, 0);
      c10 = __builtin_amdgcn_mfma_f32_16x16x32_bf16(f0, w1[ks + 0], c10, 0, 0, 0);
      c01 = __builtin_amdgcn_mfma_f32_16x16x32_bf16(f1, w0[ks + 1], c01, 0, 0, 0);
      c11 = __builtin_amdgcn_mfma_f32_16x16x32_bf16(f1, w1[ks + 1], c11, 0, 0, 0);
    }
    f32x4 t0 = c00 + c01, t1 = c10 + c11;

    // elementwise. tile0: n<8 -> f, n>=8 -> i. tile1: n<8 -> g(tanh), n>=8 -> o.
    // Lane n<8 (lg<2) OWNS col h0w+n: per-lane tagged 4B atomic swap
    // (fire-and-forget; 8 adjacent lanes = one 32B span) — no pack shuffles.
    const u32 tg = ((u32)(t + 1)) << 16;
    u32* hw = hseq + (size_t)((t + 1) & 1) * 65536 + (size_t)g * 8192;
    float ohv[4];
    #pragma unroll
    for (int r = 0; r < 4; ++r) {
      float x0 = t0[r], x1 = t1[r];
      float y0 = 1.f / (1.f + __expf(-x0));
      float s1 = (n < 8) ? 2.f * x1 : x1;
      float sg1 = 1.f / (1.f + __expf(-s1));
      float y1 = (n < 8) ? (2.f * sg1 - 1.f) : sg1;
      float iv = __shfl(y0, l | 8, 64);              // i-gate, same h-col
      float ov = __shfl(y1, l | 8, 64);              // o-gate, same h-col
      float c = y0 * cx[r] + iv * y1;                // valid on n<8 lanes
      cx[r] = c;
      float th = 2.f / (1.f + __expf(-2.f * c)) - 1.f;
      float hv = ov * th;
      ohv[r] = hv;

      if (n < 8 && lg < 2) {
        int row = lg * 4 + r;
        u32 pk = tg | (u32)f2bf(hv);
        u32* dp = hw + row * 1024 + h0w + n;
        asm volatile("global_atomic_swap %0, %1, off"
                     :: "v"(dp), "v"(pk) : "memory");
      }
      if (t == T_STEPS - 1 && n < 8 && lg < 2) {
        int ba = g * 8 + lg * 4 + r;
        out[(size_t)T_STEPS * BATCH * HDIM + (size_t)ba * HDIM + h0w + n] = hv;
        out[(size_t)T_STEPS * BATCH * HDIM + (size_t)BATCH * HDIM
            + (size_t)ba * HDIM + h0w + n] = c;
      }
    }

    // off the visibility path: per-lane out[] stores (plain cached)
    if (n < 8 && lg < 2) {
      int ba0 = g * 8 + lg * 4;
      #pragma unroll
      for (int r = 0; r < 4; ++r)
        out[((size_t)t * BATCH + ba0 + r) * HDIM + h0w + n] = ohv[r];
    }
  }
}

// ---------------- launch ----------------
extern "C" void kernel_launch(void* const* d_in, const int* in_sizes, int n_in,
                              void* d_out, int out_size, void* d_ws, size_t ws_size,
                              hipStream_t stream) {
  const float* x  = (const float*)d_in[0];   // [512][64][512]
  const float* W  = (const float*)d_in[1];   // [4096][1536]
  const float* b  = (const float*)d_in[2];   // [4096]
  float* out = (float*)d_out;
  char* ws = (char*)d_ws;

  u16* Gb   = (u16*)(ws + GB_OFF);
  u16* Xb   = (u16*)(ws + XB_OFF);
  u16* Wxb  = (u16*)(ws + WX_OFF);
  u32* hseq = (u32*)(ws + HSEQ_OFF);

  // A: convert X and Wx to bf16
  k_cvt4<<<2048, 256, 0, stream>>>(x, Xb, (T_STEPS * BATCH * IDIM) / 4);
  k_cvt_wx<<<(GDIM * (IDIM / 4) + 255) / 256, 256, 0, stream>>>(W, Wxb);

  // B: Gx = X @ Wx^T + b  (consumes Xb and Wxb; both dead afterwards)
  dim3 gB(256, 32);
  k_gemm_gx<<<gB, 256, 0, stream>>>(Xb, Wxb, b, Gb);

  // zero tagged h-exchange buffers (overlaid on dead Wx region) after the GEMM
  k_zero<<<128, 256, 0, stream>>>(hseq, 2 * 8 * 8 * 1024);

  // C: persistent recurrent kernel
  k_lstm<<<NWG, 256, 0, stream>>>(Gb, (const float*)W, hseq, out);
}

// Round 10
// 2936.119 us; speedup vs baseline: 1.0256x; 1.0256x over previous
//
#include <hip/hip_runtime.h>
#include <stdint.h>

typedef unsigned int u32;
typedef unsigned long long u64;
typedef unsigned short u16;
typedef __attribute__((ext_vector_type(8))) short bf16x8;
typedef __attribute__((ext_vector_type(4))) float f32x4;
typedef __attribute__((ext_vector_type(2))) float f32x2;
typedef __attribute__((ext_vector_type(4))) u16 u16x4;

// Problem constants
#define T_STEPS 512
#define BATCH   64
#define IDIM    512
#define HDIM    1024
#define GDIM    4096   // 4*H
#define KDIM    1536   // I+H
#define NWG     256    // 8 batch-groups x 32 h-shards, 1 WG/CU (proven chassis)

// ws layout (bytes)
#define GB_OFF  0u                    // Gx bf16 [32768][4096]  = 268435456
#define XB_OFF  268435456u            // X bf16  [32768][512]   = 33554432
#define WX_OFF  301989888u            // Wx bf16 [4096][512]    = 4194304 (dead after gemm)
// tagged h exchange overlays the dead Wx region after k_gemm_gx:
// u32 [2][8 groups][8 rows][1024 cols] = 524288 bytes
#define HSEQ_OFF WX_OFF

__device__ __forceinline__ u16 f2bf(float f) {
  union { float f; u32 u; } v; v.f = f;
  return (u16)((v.u + 0x7fffu + ((v.u >> 16) & 1u)) >> 16);   // RNE
}
__device__ __forceinline__ float bf2f(u16 h) {
  union { u32 u; float f; } v; v.u = ((u32)h) << 16; return v.f;
}
__device__ __forceinline__ u32 FU(float f) {
  union { float f; u32 u; } v; v.f = f; return v.u;
}
__device__ __forceinline__ float UF(u32 u) {
  union { u32 u; float f; } v; v.u = u; return v.f;
}

#define GLDS(g, l) __builtin_amdgcn_global_load_lds( \
    (const __attribute__((address_space(1))) u32*)(g), \
    (__attribute__((address_space(3))) u32*)(l), 16, 0, 0)

// ---------------- Phase A: conversions / init ----------------
__global__ void k_cvt4(const float* __restrict__ src, u16* __restrict__ dst, int n4) {
  int i = blockIdx.x * blockDim.x + threadIdx.x;
  int stride = gridDim.x * blockDim.x;
  for (; i < n4; i += stride) {
    float4 v = reinterpret_cast<const float4*>(src)[i];
    u16x4 o; o.x = f2bf(v.x); o.y = f2bf(v.y); o.z = f2bf(v.z); o.w = f2bf(v.w);
    reinterpret_cast<u16x4*>(dst)[i] = o;
  }
}

__global__ void k_cvt_wx(const float* __restrict__ W, u16* __restrict__ wxb) {
  int i = blockIdx.x * blockDim.x + threadIdx.x;   // over 4096*128 float4 groups
  if (i >= GDIM * (IDIM / 4)) return;
  int row = i >> 7, cg = i & 127;
  float4 v = *reinterpret_cast<const float4*>(W + (size_t)row * KDIM + cg * 4);
  u16x4 o; o.x = f2bf(v.x); o.y = f2bf(v.y); o.z = f2bf(v.z); o.w = f2bf(v.w);
  *reinterpret_cast<u16x4*>(wxb + (size_t)row * IDIM + cg * 4) = o;
}

__global__ void k_zero(u32* __restrict__ p, int n) {
  int i = blockIdx.x * blockDim.x + threadIdx.x;
  int stride = gridDim.x * blockDim.x;
  for (; i < n; i += stride) p[i] = 0u;
}

// ---------------- Phase B: Gx = Xbf16 @ Wx^T + b (bf16 out) ----------------
// M=32768, N=4096, K=512. 128x128 tile, BK=64, 4 waves each 64x64.
__global__ void k_gemm_gx(const u16* __restrict__ Xb, const u16* __restrict__ Wxb,
                          const float* __restrict__ bias, u16* __restrict__ Gb) {
  __shared__ u16 lA[128 * 64];
  __shared__ u16 lB[128 * 64];
  const int tid = threadIdx.x;
  const int wv = tid >> 6, l = tid & 63;
  const int ln = l & 15, lg = l >> 4;
  const int m0 = blockIdx.x * 128, n0 = blockIdx.y * 128;
  const int wr = wv >> 1, wc = wv & 1;

  f32x4 acc[4][4];
  #pragma unroll
  for (int mi = 0; mi < 4; ++mi)
    #pragma unroll
    for (int nj = 0; nj < 4; ++nj) acc[mi][nj] = (f32x4){0.f, 0.f, 0.f, 0.f};

  for (int kt = 0; kt < 8; ++kt) {
    #pragma unroll
    for (int it = 0; it < 4; ++it) {
      int off = it * 4096 + tid * 16;      // byte offset in 16KB tile
      int row = off >> 7;                  // 128 B per row (64 bf16)
      int col = (off & 127) >> 1;          // bf16 col
      GLDS(Xb  + (size_t)(m0 + row) * IDIM + kt * 64 + col, (char*)lA + off);
      GLDS(Wxb + (size_t)(n0 + row) * IDIM + kt * 64 + col, (char*)lB + off);
    }
    asm volatile("s_waitcnt vmcnt(0)" ::: "memory");
    __syncthreads();
    #pragma unroll
    for (int ks = 0; ks < 2; ++ks) {
      bf16x8 af[4], bfr[4];
      #pragma unroll
      for (int mi = 0; mi < 4; ++mi)
        af[mi] = *reinterpret_cast<const bf16x8*>(&lA[(wr * 64 + mi * 16 + ln) * 64 + ks * 32 + lg * 8]);
      #pragma unroll
      for (int nj = 0; nj < 4; ++nj)
        bfr[nj] = *reinterpret_cast<const bf16x8*>(&lB[(wc * 64 + nj * 16 + ln) * 64 + ks * 32 + lg * 8]);
      #pragma unroll
      for (int mi = 0; mi < 4; ++mi)
        #pragma unroll
        for (int nj = 0; nj < 4; ++nj)
          acc[mi][nj] = __builtin_amdgcn_mfma_f32_16x16x32_bf16(af[mi], bfr[nj], acc[mi][nj], 0, 0, 0);
    }
    __syncthreads();
  }
  float bv[4];
  #pragma unroll
  for (int nj = 0; nj < 4; ++nj) bv[nj] = bias[n0 + wc * 64 + nj * 16 + ln];
  #pragma unroll
  for (int mi = 0; mi < 4; ++mi)
    #pragma unroll
    for (int r = 0; r < 4; ++r) {
      int m = m0 + wr * 64 + mi * 16 + lg * 4 + r;
      #pragma unroll
      for (int nj = 0; nj < 4; ++nj)
        Gb[(size_t)m * GDIM + n0 + wc * 64 + nj * 16 + ln] = f2bf(acc[mi][nj][r] + bv[nj]);
    }
}

// ---------------- Phase C: persistent recurrent kernel ----------------
// 256 WGs = 8 batch-groups(g = w&7: 8 rows) x 32 h-shards(j = w>>3: 32 h).
// DATA IS THE FLAG, writes execute AT the IC: h exchanged as tagged u32
// (tag<<16 | bf16) via global_atomic_swap_x2 (8B atomic: tag+payload
// indivisible; ack==visible — proven R6/R7). NO drain, NO release barrier,
// NO flag. Consumers poll the contiguous 32KB tagged group slice with
// lane-linear coalesced dwordx4 loads (sc0 sc1), accept chunk iff all 4
// tags == t, re-issue only unaccepted chunks. Double-buffered over t&1.
// LDS As double-buffered -> exactly ONE __syncthreads per step.
// Lessons locked in: R8 (per-lane 4B swaps double atomic transactions, +35%),
// R9 (inline-asm prefetch at 256-VGPR cap -> spill-before-return corruption):
// Gx prefetch stays PLAIN C loads (compiler-tracked waitcnt, spill-safe).
__launch_bounds__(256, 1)
__global__ void k_lstm(const u16* __restrict__ Gb,    // [32768][4096] bf16
                       const float* __restrict__ W,   // [4096][1536] fp32
                       u32* __restrict__ hseq,        // [2][8][8][1024] tagged u32
                       float* __restrict__ out) {
  __shared__ f32x4 As[2][2048];   // 2 x 32 KB; slot byte = ((c8*16+row)<<4) ^ ((c8&7)<<4)
  const int tid = threadIdx.x;
  const int w = blockIdx.x;
  const int g = w & 7;                           // batch group: rows [8g, 8g+8)
  const int j = w >> 3;                          // h-shard: h [32j, 32j+32)
  const int wv = tid >> 6, l = tid & 63;
  const int n = l & 15, lg = l >> 4;
  const int h0w = j * 32 + wv * 8;               // this wave's 8 h-cols
  const int jcol0 = (n >> 3) * HDIM + h0w + (n & 7);        // f / i gate rows
  const int jcol1 = (2 + (n >> 3)) * HDIM + h0w + (n & 7);  // g / o gate rows

  // --- preload W_h fragments into registers (once): 2 x 32 x bf16x8 ---
  bf16x8 w0[32], w1[32];
  #pragma unroll
  for (int ks = 0; ks < 32; ++ks) {
    const float* wp = W + (size_t)jcol0 * KDIM + IDIM + ks * 32 + lg * 8;
    float4 v0 = *reinterpret_cast<const float4*>(wp);
    float4 v1 = *reinterpret_cast<const float4*>(wp + 4);
    bf16x8 fr;
    fr[0] = (short)f2bf(v0.x); fr[1] = (short)f2bf(v0.y);
    fr[2] = (short)f2bf(v0.z); fr[3] = (short)f2bf(v0.w);
    fr[4] = (short)f2bf(v1.x); fr[5] = (short)f2bf(v1.y);
    fr[6] = (short)f2bf(v1.z); fr[7] = (short)f2bf(v1.w);
    w0[ks] = fr;
  }
  #pragma unroll
  for (int ks = 0; ks < 32; ++ks) {
    const float* wp = W + (size_t)jcol1 * KDIM + IDIM + ks * 32 + lg * 8;
    float4 v0 = *reinterpret_cast<const float4*>(wp);
    float4 v1 = *reinterpret_cast<const float4*>(wp + 4);
    bf16x8 fr;
    fr[0] = (short)f2bf(v0.x); fr[1] = (short)f2bf(v0.y);
    fr[2] = (short)f2bf(v0.z); fr[3] = (short)f2bf(v0.w);
    fr[4] = (short)f2bf(v1.x); fr[5] = (short)f2bf(v1.y);
    fr[6] = (short)f2bf(v1.z); fr[7] = (short)f2bf(v1.w);
    w1[ks] = fr;
  }

  // zero BOTH As buffers once: pad rows (slot row>=8) must read as 0 forever;
  // staged writes (row<8) only touch row<8 slots (swizzle keeps q^(c8&7)<8)
  {
    f32x4* ap = &As[0][0];
    #pragma unroll
    for (int i = 0; i < 16; ++i)
      ap[i * 256 + tid] = (f32x4){0.f, 0.f, 0.f, 0.f};
  }
  __syncthreads();

  float cx[4] = {0.f, 0.f, 0.f, 0.f};

  // Gx(0) prefetch into registers (plain cached loads)
  u16 ga[4] = {0, 0, 0, 0}, gb_[4] = {0, 0, 0, 0};
  if (lg < 2) {
    #pragma unroll
    for (int r = 0; r < 4; ++r) {
      int ba = g * 8 + lg * 4 + r;
      ga[r]  = Gb[(size_t)ba * GDIM + jcol0];
      gb_[r] = Gb[(size_t)ba * GDIM + jcol1];
    }
  }

  #pragma unroll 1
  for (int t = 0; t < T_STEPS; ++t) {
    // ---- tagged-data poll: coalesced read of the 32KB group slice ----
    // thread tid owns chunk (row q, cols 4*tid..4*tid+4) for q = 0..7.
    const char* bbase = (const char*)(hseq + (size_t)(t & 1) * 65536
                                      + (size_t)g * 8192);
    const u32 tt = (u32)t << 16;
    f32x4 ld[8];
    u32 need = 0xffu, spin = 0;
    while (true) {
      #pragma unroll
      for (int q = 0; q < 8; ++q)
        if (need & (1u << q))
          asm volatile("global_load_dwordx4 %0, %1, off sc0 sc1"
                       : "=&v"(ld[q]) : "v"(bbase + q * 4096 + tid * 16) : "memory");
      asm volatile("s_waitcnt vmcnt(0)" ::: "memory");
      __builtin_amdgcn_sched_barrier(0);
      u32 bad = 0;
      #pragma unroll
      for (int q = 0; q < 8; ++q)
        if (need & (1u << q)) {
          u32 m = ((FU(ld[q].x) ^ tt) | (FU(ld[q].y) ^ tt)
                 | (FU(ld[q].z) ^ tt) | (FU(ld[q].w) ^ tt)) & 0xffff0000u;
          if (m) bad |= (1u << q);
        }
      need = bad;
      if (__all((int)(need == 0u))) break;   // wave-uniform exit
      if (++spin > (1u << 17)) break;        // bounded: fail visibly, never hang
    }

    // ---- stage payload (low16) into swizzled LDS fragment slots ----
    char* lbase = (char*)&As[t & 1][0];
    const int col8 = tid >> 1, half = tid & 1;
    const u32 sbase = (u32)(col8 * 256 + half * 8);
    #pragma unroll
    for (int q = 0; q < 8; ++q) {
      u32 a = FU(ld[q].x), b = FU(ld[q].y), c = FU(ld[q].z), d = FU(ld[q].w);
      f32x2 pk2 = { UF((a & 0xffffu) | (b << 16)), UF((c & 0xffffu) | (d << 16)) };
      u32 off = sbase + (u32)((q ^ (col8 & 7)) * 16);
      *reinterpret_cast<f32x2*>(lbase + off) = pk2;
    }
    __syncthreads();   // the ONLY barrier per step (As is double-buffered)

    // gates = Gx + hx @ Wh^T : 2 N-tiles x 32 ks, 4 independent MFMA chains
    f32x4 c00 = {bf2f(ga[0]),  bf2f(ga[1]),  bf2f(ga[2]),  bf2f(ga[3])};
    f32x4 c10 = {bf2f(gb_[0]), bf2f(gb_[1]), bf2f(gb_[2]), bf2f(gb_[3])};
    f32x4 c01 = {0.f, 0.f, 0.f, 0.f}, c11 = c01;

    // Gx(t+1): plain C loads at the consume point (ga/gb_ just died).
    // Compiler-tracked -> waitcnt before next use is automatic and spill-safe.
    {
      int tn = (t < T_STEPS - 1) ? t + 1 : t;
      if (lg < 2) {
        #pragma unroll
        for (int r = 0; r < 4; ++r) {
          int ba = g * 8 + lg * 4 + r;
          const u16* gp = Gb + ((size_t)tn * BATCH + ba) * GDIM;
          ga[r]  = gp[jcol0];
          gb_[r] = gp[jcol1];
        }
      }
    }

    #pragma unroll
    for (int ks = 0; ks < 32; ks += 2) {
      int c8a = 4 * (ks + 0) + lg;
      int c8b = 4 * (ks + 1) + lg;
      u32 ba_ = (u32)(((c8a * 16 + n) << 4) ^ ((c8a & 7) << 4));
      u32 bb_ = (u32)(((c8b * 16 + n) << 4) ^ ((c8b & 7) << 4));
      bf16x8 f0 = *reinterpret_cast<const bf16x8*>(lbase + ba_);
      bf16x8 f1 = *reinterpret_cast<const bf16x8*>(lbase + bb_);
      c00 = __builtin_amdgcn_mfma_f32_16x16x32_bf16(f0, w0[ks + 0], c00, 0, 0, 0);
      c10 = __builtin_amdgcn_mfma_f32_16x16x32_bf16(f0, w1[ks + 0], c10, 0, 0, 0);
      c01 = __builtin_amdgcn_mfma_f32_16x16x32_bf16(f1, w0[ks + 1], c01, 0, 0, 0);
      c11 = __builtin_amdgcn_mfma_f32_16x16x32_bf16(f1, w1[ks + 1], c11, 0, 0, 0);
    }
    f32x4 t0 = c00 + c01, t1 = c10 + c11;

    // elementwise. tile0: n<8 -> f, n>=8 -> i. tile1: n<8 -> g(tanh), n>=8 -> o.
    // tagged h release: fire-and-forget swap_x2 (2 tagged cols / 8B atomic).
    const u32 tg = ((u32)(t + 1)) << 16;
    u32* hw = hseq + (size_t)((t + 1) & 1) * 65536 + (size_t)g * 8192;
    float o0[4], o1[4];                     // buffered out values (stored later)
    #pragma unroll
    for (int r = 0; r < 4; ++r) {
      float x0 = t0[r], x1 = t1[r];
      float y0 = 1.f / (1.f + __expf(-x0));
      float s1 = (n < 8) ? 2.f * x1 : x1;
      float sg1 = 1.f / (1.f + __expf(-s1));
      float y1 = (n < 8) ? (2.f * sg1 - 1.f) : sg1;
      float iv = __shfl(y0, l | 8, 64);              // i-gate, same h-col
      float ov = __shfl(y1, l | 8, 64);              // o-gate, same h-col
      float c = y0 * cx[r] + iv * y1;                // valid on n<8 lanes
      cx[r] = c;
      float th = 2.f / (1.f + __expf(-2.f * c)) - 1.f;
      float hv = ov * th;

      // col-pair pack: lane n<4 handles cols h0w+2n, h0w+2n+1
      float s0 = __shfl(hv, (l & 48) | (2 * n),     64);
      float s1v = __shfl(hv, (l & 48) | (2 * n + 1), 64);
      o0[r] = s0; o1[r] = s1v;

      if (n < 4 && lg < 2) {
        int row = lg * 4 + r;
        u64 pk = (u64)(tg | (u32)f2bf(s0))
               | ((u64)(tg | (u32)f2bf(s1v)) << 32);
        u32* dp = hw + row * 1024 + h0w + 2 * n;
        asm volatile("global_atomic_swap_x2 %0, %1, off"
                     :: "v"(dp), "v"(pk) : "memory");
      }
      if (t == T_STEPS - 1) {
        float q0 = __shfl(c, (l & 48) | (2 * n),     64);
        float q1 = __shfl(c, (l & 48) | (2 * n + 1), 64);
        if (n < 4 && lg < 2) {
          int ba = g * 8 + lg * 4 + r;
          float* cp = out + (size_t)T_STEPS * BATCH * HDIM + (size_t)BATCH * HDIM
                    + (size_t)ba * HDIM + h0w + 2 * n;
          f32x2 c2 = {q0, q1};
          *reinterpret_cast<f32x2*>(cp) = c2;
          float* hp = out + (size_t)T_STEPS * BATCH * HDIM
                    + (size_t)ba * HDIM + h0w + 2 * n;
          f32x2 h2 = {s0, s1v};
          *reinterpret_cast<f32x2*>(hp) = h2;
        }
      }
    }

    // ---- OFF the critical path: out[] stores (plain cached) ----
    if (n < 4 && lg < 2) {
      int ba0 = g * 8 + lg * 4;
      #pragma unroll
      for (int r = 0; r < 4; ++r) {
        float* op = out + ((size_t)t * BATCH + ba0 + r) * HDIM + h0w + 2 * n;
        f32x2 o2 = {o0[r], o1[r]};
        *reinterpret_cast<f32x2*>(op) = o2;
      }
    }
  }
}

// ---------------- launch ----------------
extern "C" void kernel_launch(void* const* d_in, const int* in_sizes, int n_in,
                              void* d_out, int out_size, void* d_ws, size_t ws_size,
                              hipStream_t stream) {
  const float* x  = (const float*)d_in[0];   // [512][64][512]
  const float* W  = (const float*)d_in[1];   // [4096][1536]
  const float* b  = (const float*)d_in[2];   // [4096]
  float* out = (float*)d_out;
  char* ws = (char*)d_ws;

  u16* Gb   = (u16*)(ws + GB_OFF);
  u16* Xb   = (u16*)(ws + XB_OFF);
  u16* Wxb  = (u16*)(ws + WX_OFF);
  u32* hseq = (u32*)(ws + HSEQ_OFF);

  // A: convert X and Wx to bf16
  k_cvt4<<<2048, 256, 0, stream>>>(x, Xb, (T_STEPS * BATCH * IDIM) / 4);
  k_cvt_wx<<<(GDIM * (IDIM / 4) + 255) / 256, 256, 0, stream>>>(W, Wxb);

  // B: Gx = X @ Wx^T + b  (consumes Xb and Wxb; both dead afterwards)
  dim3 gB(256, 32);
  k_gemm_gx<<<gB, 256, 0, stream>>>(Xb, Wxb, b, Gb);

  // zero tagged h-exchange buffers (overlaid on dead Wx region) after the GEMM
  k_zero<<<128, 256, 0, stream>>>(hseq, 2 * 8 * 8 * 1024);

  // C: persistent recurrent kernel
  k_lstm<<<NWG, 256, 0, stream>>>(Gb, (const float*)W, hseq, out);
}

// Round 11
// 2237.041 us; speedup vs baseline: 1.3460x; 1.3125x over previous
//
#include <hip/hip_runtime.h>
#include <stdint.h>

typedef unsigned int u32;
typedef unsigned long long u64;
typedef unsigned short u16;
typedef __attribute__((ext_vector_type(8))) short bf16x8;
typedef __attribute__((ext_vector_type(4))) float f32x4;
typedef __attribute__((ext_vector_type(2))) float f32x2;
typedef __attribute__((ext_vector_type(4))) u16 u16x4;

// Problem constants
#define T_STEPS 512
#define BATCH   64
#define IDIM    512
#define HDIM    1024
#define GDIM    4096   // 4*H
#define KDIM    1536   // I+H
#define NWG     256    // 8 batch-groups x 32 h-shards, 1 WG/CU (proven chassis)

// ws layout (bytes)
#define GB_OFF  0u                    // Gx bf16 [32768][4096]  = 268435456
#define XB_OFF  268435456u            // X bf16  [32768][512]   = 33554432
#define WX_OFF  301989888u            // Wx bf16 [4096][512]    = 4194304 (dead after gemm)
// tagged h exchange overlays the dead Wx region after k_gemm_gx:
// u32 [2][8 groups][8 rows][1024 cols] = 524288 bytes
#define HSEQ_OFF WX_OFF

__device__ __forceinline__ u16 f2bf(float f) {
  union { float f; u32 u; } v; v.f = f;
  return (u16)((v.u + 0x7fffu + ((v.u >> 16) & 1u)) >> 16);   // RNE
}
__device__ __forceinline__ float bf2f(u16 h) {
  union { u32 u; float f; } v; v.u = ((u32)h) << 16; return v.f;
}
__device__ __forceinline__ u32 FU(float f) {
  union { float f; u32 u; } v; v.f = f; return v.u;
}
__device__ __forceinline__ float UF(u32 u) {
  union { u32 u; float f; } v; v.u = u; return v.f;
}

#define GLDS(g, l) __builtin_amdgcn_global_load_lds( \
    (const __attribute__((address_space(1))) u32*)(g), \
    (__attribute__((address_space(3))) u32*)(l), 16, 0, 0)

// ---------------- Phase A: conversions / init ----------------
__global__ void k_cvt4(const float* __restrict__ src, u16* __restrict__ dst, int n4) {
  int i = blockIdx.x * blockDim.x + threadIdx.x;
  int stride = gridDim.x * blockDim.x;
  for (; i < n4; i += stride) {
    float4 v = reinterpret_cast<const float4*>(src)[i];
    u16x4 o; o.x = f2bf(v.x); o.y = f2bf(v.y); o.z = f2bf(v.z); o.w = f2bf(v.w);
    reinterpret_cast<u16x4*>(dst)[i] = o;
  }
}

__global__ void k_cvt_wx(const float* __restrict__ W, u16* __restrict__ wxb) {
  int i = blockIdx.x * blockDim.x + threadIdx.x;   // over 4096*128 float4 groups
  if (i >= GDIM * (IDIM / 4)) return;
  int row = i >> 7, cg = i & 127;
  float4 v = *reinterpret_cast<const float4*>(W + (size_t)row * KDIM + cg * 4);
  u16x4 o; o.x = f2bf(v.x); o.y = f2bf(v.y); o.z = f2bf(v.z); o.w = f2bf(v.w);
  *reinterpret_cast<u16x4*>(wxb + (size_t)row * IDIM + cg * 4) = o;
}

__global__ void k_zero(u32* __restrict__ p, int n) {
  int i = blockIdx.x * blockDim.x + threadIdx.x;
  int stride = gridDim.x * blockDim.x;
  for (; i < n; i += stride) p[i] = 0u;
}

// ---------------- Phase B: Gx = Xbf16 @ Wx^T + b (bf16 out) ----------------
// M=32768, N=4096, K=512. 128x128 tile, BK=64, 4 waves each 64x64.
__global__ void k_gemm_gx(const u16* __restrict__ Xb, const u16* __restrict__ Wxb,
                          const float* __restrict__ bias, u16* __restrict__ Gb) {
  __shared__ u16 lA[128 * 64];
  __shared__ u16 lB[128 * 64];
  const int tid = threadIdx.x;
  const int wv = tid >> 6, l = tid & 63;
  const int ln = l & 15, lg = l >> 4;
  const int m0 = blockIdx.x * 128, n0 = blockIdx.y * 128;
  const int wr = wv >> 1, wc = wv & 1;

  f32x4 acc[4][4];
  #pragma unroll
  for (int mi = 0; mi < 4; ++mi)
    #pragma unroll
    for (int nj = 0; nj < 4; ++nj) acc[mi][nj] = (f32x4){0.f, 0.f, 0.f, 0.f};

  for (int kt = 0; kt < 8; ++kt) {
    #pragma unroll
    for (int it = 0; it < 4; ++it) {
      int off = it * 4096 + tid * 16;      // byte offset in 16KB tile
      int row = off >> 7;                  // 128 B per row (64 bf16)
      int col = (off & 127) >> 1;          // bf16 col
      GLDS(Xb  + (size_t)(m0 + row) * IDIM + kt * 64 + col, (char*)lA + off);
      GLDS(Wxb + (size_t)(n0 + row) * IDIM + kt * 64 + col, (char*)lB + off);
    }
    asm volatile("s_waitcnt vmcnt(0)" ::: "memory");
    __syncthreads();
    #pragma unroll
    for (int ks = 0; ks < 2; ++ks) {
      bf16x8 af[4], bfr[4];
      #pragma unroll
      for (int mi = 0; mi < 4; ++mi)
        af[mi] = *reinterpret_cast<const bf16x8*>(&lA[(wr * 64 + mi * 16 + ln) * 64 + ks * 32 + lg * 8]);
      #pragma unroll
      for (int nj = 0; nj < 4; ++nj)
        bfr[nj] = *reinterpret_cast<const bf16x8*>(&lB[(wc * 64 + nj * 16 + ln) * 64 + ks * 32 + lg * 8]);
      #pragma unroll
      for (int mi = 0; mi < 4; ++mi)
        #pragma unroll
        for (int nj = 0; nj < 4; ++nj)
          acc[mi][nj] = __builtin_amdgcn_mfma_f32_16x16x32_bf16(af[mi], bfr[nj], acc[mi][nj], 0, 0, 0);
    }
    __syncthreads();
  }
  float bv[4];
  #pragma unroll
  for (int nj = 0; nj < 4; ++nj) bv[nj] = bias[n0 + wc * 64 + nj * 16 + ln];
  #pragma unroll
  for (int mi = 0; mi < 4; ++mi)
    #pragma unroll
    for (int r = 0; r < 4; ++r) {
      int m = m0 + wr * 64 + mi * 16 + lg * 4 + r;
      #pragma unroll
      for (int nj = 0; nj < 4; ++nj)
        Gb[(size_t)m * GDIM + n0 + wc * 64 + nj * 16 + ln] = f2bf(acc[mi][nj][r] + bv[nj]);
    }
}

// ---------------- Phase C: persistent recurrent kernel ----------------
// 256 WGs = 8 batch-groups(g = w&7: 8 rows) x 32 h-shards(j = w>>3: 32 h).
// DATA IS THE FLAG, writes execute AT the IC: h exchanged as tagged u32
// (tag<<16 | bf16) via global_atomic_swap_x2 (8B atomic: tag+payload
// indivisible; ack==visible — proven R6/R7). NO drain, NO release barrier,
// NO flag. Consumers poll the contiguous 32KB tagged group slice with
// lane-linear coalesced dwordx4 loads (sc0 sc1), accept chunk iff all 4
// tags == t, re-issue only unaccepted chunks. Double-buffered over t&1.
// LDS As double-buffered -> exactly ONE __syncthreads per step.
// ORDERING LESSONS (locked): per-wave VMEM issue is IN-ORDER, so the release
// swaps must be the FIRST vmem ops after the gates — out[] stores and the
// Gx(t+1) prefetch go AFTER them (R10: prefetch-before-swaps cost +30%).
// R8: per-lane 4B swaps double atomic transactions (+35%) — keep swap_x2.
// R9: inline-asm prefetch at 256-VGPR cap -> spill-before-return corruption —
// keep the prefetch as PLAIN C loads (compiler-tracked, spill-safe).
__launch_bounds__(256, 1)
__global__ void k_lstm(const u16* __restrict__ Gb,    // [32768][4096] bf16
                       const float* __restrict__ W,   // [4096][1536] fp32
                       u32* __restrict__ hseq,        // [2][8][8][1024] tagged u32
                       float* __restrict__ out) {
  __shared__ f32x4 As[2][2048];   // 2 x 32 KB; slot byte = ((c8*16+row)<<4) ^ ((c8&7)<<4)
  const int tid = threadIdx.x;
  const int w = blockIdx.x;
  const int g = w & 7;                           // batch group: rows [8g, 8g+8)
  const int j = w >> 3;                          // h-shard: h [32j, 32j+32)
  const int wv = tid >> 6, l = tid & 63;
  const int n = l & 15, lg = l >> 4;
  const int h0w = j * 32 + wv * 8;               // this wave's 8 h-cols
  const int jcol0 = (n >> 3) * HDIM + h0w + (n & 7);        // f / i gate rows
  const int jcol1 = (2 + (n >> 3)) * HDIM + h0w + (n & 7);  // g / o gate rows

  // --- preload W_h fragments into registers (once): 2 x 32 x bf16x8 ---
  bf16x8 w0[32], w1[32];
  #pragma unroll
  for (int ks = 0; ks < 32; ++ks) {
    const float* wp = W + (size_t)jcol0 * KDIM + IDIM + ks * 32 + lg * 8;
    float4 v0 = *reinterpret_cast<const float4*>(wp);
    float4 v1 = *reinterpret_cast<const float4*>(wp + 4);
    bf16x8 fr;
    fr[0] = (short)f2bf(v0.x); fr[1] = (short)f2bf(v0.y);
    fr[2] = (short)f2bf(v0.z); fr[3] = (short)f2bf(v0.w);
    fr[4] = (short)f2bf(v1.x); fr[5] = (short)f2bf(v1.y);
    fr[6] = (short)f2bf(v1.z); fr[7] = (short)f2bf(v1.w);
    w0[ks] = fr;
  }
  #pragma unroll
  for (int ks = 0; ks < 32; ++ks) {
    const float* wp = W + (size_t)jcol1 * KDIM + IDIM + ks * 32 + lg * 8;
    float4 v0 = *reinterpret_cast<const float4*>(wp);
    float4 v1 = *reinterpret_cast<const float4*>(wp + 4);
    bf16x8 fr;
    fr[0] = (short)f2bf(v0.x); fr[1] = (short)f2bf(v0.y);
    fr[2] = (short)f2bf(v0.z); fr[3] = (short)f2bf(v0.w);
    fr[4] = (short)f2bf(v1.x); fr[5] = (short)f2bf(v1.y);
    fr[6] = (short)f2bf(v1.z); fr[7] = (short)f2bf(v1.w);
    w1[ks] = fr;
  }

  // zero BOTH As buffers once: pad rows (slot row>=8) must read as 0 forever;
  // staged writes (row<8) only touch row<8 slots (swizzle keeps q^(c8&7)<8)
  {
    f32x4* ap = &As[0][0];
    #pragma unroll
    for (int i = 0; i < 16; ++i)
      ap[i * 256 + tid] = (f32x4){0.f, 0.f, 0.f, 0.f};
  }
  __syncthreads();

  float cx[4] = {0.f, 0.f, 0.f, 0.f};

  // Gx(0) prefetch into registers (plain cached loads)
  u16 ga[4] = {0, 0, 0, 0}, gb_[4] = {0, 0, 0, 0};
  if (lg < 2) {
    #pragma unroll
    for (int r = 0; r < 4; ++r) {
      int ba = g * 8 + lg * 4 + r;
      ga[r]  = Gb[(size_t)ba * GDIM + jcol0];
      gb_[r] = Gb[(size_t)ba * GDIM + jcol1];
    }
  }

  #pragma unroll 1
  for (int t = 0; t < T_STEPS; ++t) {
    // ---- tagged-data poll: coalesced read of the 32KB group slice ----
    // thread tid owns chunk (row q, cols 4*tid..4*tid+4) for q = 0..7.
    const char* bbase = (const char*)(hseq + (size_t)(t & 1) * 65536
                                      + (size_t)g * 8192);
    const u32 tt = (u32)t << 16;
    f32x4 ld[8];
    u32 need = 0xffu, spin = 0;
    while (true) {
      #pragma unroll
      for (int q = 0; q < 8; ++q)
        if (need & (1u << q))
          asm volatile("global_load_dwordx4 %0, %1, off sc0 sc1"
                       : "=&v"(ld[q]) : "v"(bbase + q * 4096 + tid * 16) : "memory");
      asm volatile("s_waitcnt vmcnt(0)" ::: "memory");
      __builtin_amdgcn_sched_barrier(0);
      u32 bad = 0;
      #pragma unroll
      for (int q = 0; q < 8; ++q)
        if (need & (1u << q)) {
          u32 m = ((FU(ld[q].x) ^ tt) | (FU(ld[q].y) ^ tt)
                 | (FU(ld[q].z) ^ tt) | (FU(ld[q].w) ^ tt)) & 0xffff0000u;
          if (m) bad |= (1u << q);
        }
      need = bad;
      if (__all((int)(need == 0u))) break;   // wave-uniform exit
      if (++spin > (1u << 17)) break;        // bounded: fail visibly, never hang
    }

    // ---- stage payload (low16) into swizzled LDS fragment slots ----
    char* lbase = (char*)&As[t & 1][0];
    const int col8 = tid >> 1, half = tid & 1;
    const u32 sbase = (u32)(col8 * 256 + half * 8);
    #pragma unroll
    for (int q = 0; q < 8; ++q) {
      u32 a = FU(ld[q].x), b = FU(ld[q].y), c = FU(ld[q].z), d = FU(ld[q].w);
      f32x2 pk2 = { UF((a & 0xffffu) | (b << 16)), UF((c & 0xffffu) | (d << 16)) };
      u32 off = sbase + (u32)((q ^ (col8 & 7)) * 16);
      *reinterpret_cast<f32x2*>(lbase + off) = pk2;
    }
    __syncthreads();   // the ONLY barrier per step (As is double-buffered)

    // gates = Gx + hx @ Wh^T : 2 N-tiles x 32 ks, 4 independent MFMA chains
    f32x4 c00 = {bf2f(ga[0]),  bf2f(ga[1]),  bf2f(ga[2]),  bf2f(ga[3])};
    f32x4 c10 = {bf2f(gb_[0]), bf2f(gb_[1]), bf2f(gb_[2]), bf2f(gb_[3])};
    f32x4 c01 = {0.f, 0.f, 0.f, 0.f}, c11 = c01;

    #pragma unroll
    for (int ks = 0; ks < 32; ks += 2) {
      int c8a = 4 * (ks + 0) + lg;
      int c8b = 4 * (ks + 1) + lg;
      u32 ba_ = (u32)(((c8a * 16 + n) << 4) ^ ((c8a & 7) << 4));
      u32 bb_ = (u32)(((c8b * 16 + n) << 4) ^ ((c8b & 7) << 4));
      bf16x8 f0 = *reinterpret_cast<const bf16x8*>(lbase + ba_);
      bf16x8 f1 = *reinterpret_cast<const bf16x8*>(lbase + bb_);
      c00 = __builtin_amdgcn_mfma_f32_16x16x32_bf16(f0, w0[ks + 0], c00, 0, 0, 0);
      c10 = __builtin_amdgcn_mfma_f32_16x16x32_bf16(f0, w1[ks + 0], c10, 0, 0, 0);
      c01 = __builtin_amdgcn_mfma_f32_16x16x32_bf16(f1, w0[ks + 1], c01, 0, 0, 0);
      c11 = __builtin_amdgcn_mfma_f32_16x16x32_bf16(f1, w1[ks + 1], c11, 0, 0, 0);
    }
    f32x4 t0 = c00 + c01, t1 = c10 + c11;

    // elementwise. tile0: n<8 -> f, n>=8 -> i. tile1: n<8 -> g(tanh), n>=8 -> o.
    // tagged h release: fire-and-forget swap_x2 (2 tagged cols / 8B atomic) —
    // FIRST vmem ops after the gates (in-order VMEM: nothing may precede them).
    const u32 tg = ((u32)(t + 1)) << 16;
    u32* hw = hseq + (size_t)((t + 1) & 1) * 65536 + (size_t)g * 8192;
    float o0[4], o1[4];                     // buffered out values (stored later)
    #pragma unroll
    for (int r = 0; r < 4; ++r) {
      float x0 = t0[r], x1 = t1[r];
      float y0 = 1.f / (1.f + __expf(-x0));
      float s1 = (n < 8) ? 2.f * x1 : x1;
      float sg1 = 1.f / (1.f + __expf(-s1));
      float y1 = (n < 8) ? (2.f * sg1 - 1.f) : sg1;
      float iv = __shfl(y0, l | 8, 64);              // i-gate, same h-col
      float ov = __shfl(y1, l | 8, 64);              // o-gate, same h-col
      float c = y0 * cx[r] + iv * y1;                // valid on n<8 lanes
      cx[r] = c;
      float th = 2.f / (1.f + __expf(-2.f * c)) - 1.f;
      float hv = ov * th;

      // col-pair pack: lane n<4 handles cols h0w+2n, h0w+2n+1
      float s0 = __shfl(hv, (l & 48) | (2 * n),     64);
      float s1v = __shfl(hv, (l & 48) | (2 * n + 1), 64);
      o0[r] = s0; o1[r] = s1v;

      if (n < 4 && lg < 2) {
        int row = lg * 4 + r;
        u64 pk = (u64)(tg | (u32)f2bf(s0))
               | ((u64)(tg | (u32)f2bf(s1v)) << 32);
        u32* dp = hw + row * 1024 + h0w + 2 * n;
        asm volatile("global_atomic_swap_x2 %0, %1, off"
                     :: "v"(dp), "v"(pk) : "memory");
      }
      if (t == T_STEPS - 1) {
        float q0 = __shfl(c, (l & 48) | (2 * n),     64);
        float q1 = __shfl(c, (l & 48) | (2 * n + 1), 64);
        if (n < 4 && lg < 2) {
          int ba = g * 8 + lg * 4 + r;
          float* cp = out + (size_t)T_STEPS * BATCH * HDIM + (size_t)BATCH * HDIM
                    + (size_t)ba * HDIM + h0w + 2 * n;
          f32x2 c2 = {q0, q1};
          *reinterpret_cast<f32x2*>(cp) = c2;
          float* hp = out + (size_t)T_STEPS * BATCH * HDIM
                    + (size_t)ba * HDIM + h0w + 2 * n;
          f32x2 h2 = {s0, s1v};
          *reinterpret_cast<f32x2*>(hp) = h2;
        }
      }
    }

    // ---- OFF the critical path (AFTER the swaps): out[] stores ----
    if (n < 4 && lg < 2) {
      int ba0 = g * 8 + lg * 4;
      #pragma unroll
      for (int r = 0; r < 4; ++r) {
        float* op = out + ((size_t)t * BATCH + ba0 + r) * HDIM + h0w + 2 * n;
        f32x2 o2 = {o0[r], o1[r]};
        *reinterpret_cast<f32x2*>(op) = o2;
      }
    }
    // ---- Gx(t+1) prefetch: LAST vmem ops of the iteration (plain C loads,
    // compiler-tracked; latency hides under the next poll's spin) ----
    {
      int tn = (t < T_STEPS - 1) ? t + 1 : t;
      if (lg < 2) {
        #pragma unroll
        for (int r = 0; r < 4; ++r) {
          int ba = g * 8 + lg * 4 + r;
          const u16* gp = Gb + ((size_t)tn * BATCH + ba) * GDIM;
          ga[r]  = gp[jcol0];
          gb_[r] = gp[jcol1];
        }
      }
    }
  }
}

// ---------------- launch ----------------
extern "C" void kernel_launch(void* const* d_in, const int* in_sizes, int n_in,
                              void* d_out, int out_size, void* d_ws, size_t ws_size,
                              hipStream_t stream) {
  const float* x  = (const float*)d_in[0];   // [512][64][512]
  const float* W  = (const float*)d_in[1];   // [4096][1536]
  const float* b  = (const float*)d_in[2];   // [4096]
  float* out = (float*)d_out;
  char* ws = (char*)d_ws;

  u16* Gb   = (u16*)(ws + GB_OFF);
  u16* Xb   = (u16*)(ws + XB_OFF);
  u16* Wxb  = (u16*)(ws + WX_OFF);
  u32* hseq = (u32*)(ws + HSEQ_OFF);

  // A: convert X and Wx to bf16
  k_cvt4<<<2048, 256, 0, stream>>>(x, Xb, (T_STEPS * BATCH * IDIM) / 4);
  k_cvt_wx<<<(GDIM * (IDIM / 4) + 255) / 256, 256, 0, stream>>>(W, Wxb);

  // B: Gx = X @ Wx^T + b  (consumes Xb and Wxb; both dead afterwards)
  dim3 gB(256, 32);
  k_gemm_gx<<<gB, 256, 0, stream>>>(Xb, Wxb, b, Gb);

  // zero tagged h-exchange buffers (overlaid on dead Wx region) after the GEMM
  k_zero<<<128, 256, 0, stream>>>(hseq, 2 * 8 * 8 * 1024);

  // C: persistent recurrent kernel
  k_lstm<<<NWG, 256, 0, stream>>>(Gb, (const float*)W, hseq, out);
}